// Round 3
// baseline (1813.761 us; speedup 1.0000x reference)
//
#include <hip/hip_runtime.h>

// Problem constants
#define BS  32
#define CIN 256
#define QH  17
#define QW  17
#define HH  65
#define WW  65
#define PAD 8
#define YT  4      // y rows per block tile (each wave accumulates all 4)
#define CCHUNK 16  // channels per wave; 4 waves x 4 c-blocks cover 256
#define NVMAX 20   // max S rows needed per y-tile: YT-1 + 2*PAD + 1

// K1: main correlation for x in [0,64). wave = (b, y-tile, c-chunk), lane = x.
// Staging discipline: per channel, stage ALL needed padded S rows into the
// wave's LDS buffer, __syncthreads(), consume, __syncthreads(). Cross-lane
// LDS reads are only ever made after a block barrier — no visibility race
// (round-2 bug: compiler hoisted per-thread "non-aliasing" ds_reads above
// the same iteration's ds_writes, yielding one-row-stale windows).
__global__ __launch_bounds__(256) void corr_main(
    const float* __restrict__ Qg, const float* __restrict__ Sg,
    float* __restrict__ out)
{
  const int lane = threadIdx.x & 63;
  const int w    = threadIdx.x >> 6;

  const int bid = blockIdx.x;          // ((b*17 + yt)*4 + cb)
  const int cb  = bid & 3;
  const int t   = bid >> 2;
  const int yt  = t % 17;
  const int b   = t / 17;
  const int y0  = yt * YT;
  const int c0  = (cb * 4 + w) * CCHUNK;

  // per-wave padded row set: cols [0,8)=0, [8,73)=data, [73,96)=0
  __shared__ float sbuf[4][NVMAX][96];
  __shared__ float red[4][YT][64];     // cross-wave reduction buffer

  int vlo = y0 - PAD;            if (vlo < 0) vlo = 0;
  int vhi = y0 + (YT - 1) + PAD; if (vhi > HH - 1) vhi = HH - 1;
  const int nv = vhi - vlo + 1;        // block-uniform (<= NVMAX)

  // zero entire sbuf (incl. pads); pads stay zero (staging writes [8,73) only)
  for (int idx = threadIdx.x; idx < 4 * NVMAX * 96; idx += 256)
    ((float*)sbuf)[idx] = 0.0f;
  __syncthreads();                     // init visible to all lanes before staging

  float acc[YT] = {0.0f, 0.0f, 0.0f, 0.0f};

  for (int cc = 0; cc < CCHUNK; ++cc) {
    const int c = c0 + cc;
    const float* __restrict__ Sc = Sg + ((size_t)(b * CIN + c) * HH) * WW;
    const float* __restrict__ Qc = Qg + ((size_t)(b * CIN + c) * QH) * QW;

    // stage nv rows of this channel into the wave's buffer
    for (int vv = 0; vv < nv; ++vv) {
      const float* __restrict__ srow = Sc + (vlo + vv) * WW;
      sbuf[w][vv][PAD + lane] = srow[lane];            // srow[0..63]
      if (lane == 0) sbuf[w][vv][PAD + 64] = srow[64]; // srow[64], no overlap
    }
    __syncthreads();   // staged data visible across lanes

    for (int vv = 0; vv < nv; ++vv) {
      // lane's 17-tap window: u = lane + j - PAD -> lds col lane + j
      float s[QW];
      #pragma unroll
      for (int j = 0; j < QW; ++j) s[j] = sbuf[w][vv][lane + j];
      const int ibase = (vlo + vv) - y0 + PAD;  // i for dy = 0
      #pragma unroll
      for (int dy = 0; dy < YT; ++dy) {
        const int i = ibase - dy;
        if ((unsigned)i < (unsigned)QH) {
          const float* __restrict__ qrow = Qc + i * QW;  // wave-uniform -> s_load
          #pragma unroll
          for (int j = 0; j < QW; ++j)
            acc[dy] = fmaf(s[j], qrow[j], acc[dy]);
        }
      }
    }
    __syncthreads();   // WAR: all reads done before next channel re-stages
  }

  // reduce the 4 waves' channel-partials, then 1 atomicAdd per output per block
  #pragma unroll
  for (int dy = 0; dy < YT; ++dy) red[w][dy][lane] = acc[dy];
  __syncthreads();
  if (w == 0) {
    #pragma unroll
    for (int dy = 0; dy < YT; ++dy) {
      const int y = y0 + dy;
      if (y < HH) {
        float tsum = red[0][dy][lane] + red[1][dy][lane]
                   + red[2][dy][lane] + red[3][dy][lane];
        atomicAdd(&out[((size_t)b * HH + y) * WW + lane], tsum);
      }
    }
  }
}

// K2: x = 64 column (right edge, only taps j in [0,9) valid). wave per (b,y).
// Global reads + shuffles only — no LDS, no race surface.
__global__ __launch_bounds__(256) void corr_edge(
    const float* __restrict__ Qg, const float* __restrict__ Sg,
    float* __restrict__ out)
{
  const int lane = threadIdx.x & 63;
  const int w = threadIdx.x >> 6;
  const int wid = blockIdx.x * 4 + w;   // [0, 2080)
  const int b = wid / HH;
  const int y = wid - b * HH;
  float acc = 0.0f;
  for (int c = 0; c < CIN; ++c) {
    const float* __restrict__ Sc = Sg + ((size_t)(b * CIN + c) * HH) * WW;
    const float* __restrict__ Qc = Qg + ((size_t)(b * CIN + c) * QH) * QW;
    #pragma unroll
    for (int r = 0; r < 3; ++r) {
      const int tp = lane + r * 64;     // tap index over (i, j<9), 153 total
      if (tp < QH * 9) {
        const int i = tp / 9;
        const int j = tp - i * 9;
        const int v = y + i - PAD;
        if ((unsigned)v < (unsigned)HH)
          acc += Sc[v * WW + (WW - 9) + j] * Qc[i * QW + j];
      }
    }
  }
  #pragma unroll
  for (int off = 32; off; off >>= 1) acc += __shfl_down(acc, off, 64);
  if (lane == 0) out[((size_t)b * HH + y) * WW + (WW - 1)] = acc;
}

// K3: global sum / sum-of-squares into stats[0..1] (d_ws, zeroed beforehand)
__global__ __launch_bounds__(256) void bn_reduce(
    const float* __restrict__ x, float* __restrict__ stats, int n)
{
  float a = 0.0f, q = 0.0f;
  for (int i = blockIdx.x * blockDim.x + threadIdx.x; i < n;
       i += gridDim.x * blockDim.x) {
    float v = x[i];
    a += v; q += v * v;
  }
  #pragma unroll
  for (int off = 32; off; off >>= 1) {
    a += __shfl_down(a, off, 64);
    q += __shfl_down(q, off, 64);
  }
  __shared__ float sa[4], sq[4];
  const int w = threadIdx.x >> 6, lane = threadIdx.x & 63;
  if (lane == 0) { sa[w] = a; sq[w] = q; }
  __syncthreads();
  if (threadIdx.x == 0) {
    atomicAdd(&stats[0], sa[0] + sa[1] + sa[2] + sa[3]);
    atomicAdd(&stats[1], sq[0] + sq[1] + sq[2] + sq[3]);
  }
}

// K4: in-place training-mode BN normalize of d_out
__global__ __launch_bounds__(256) void bn_norm(
    float* __restrict__ x, const float* __restrict__ stats,
    const float* __restrict__ gamma, const float* __restrict__ beta, int n)
{
  const float invn = 1.0f / (float)n;
  const float mean = stats[0] * invn;
  const float var  = stats[1] * invn - mean * mean;
  const float inv  = rsqrtf(var + 1e-5f);
  const float g  = gamma[0] * inv;
  const float be = beta[0] - mean * g;
  for (int i = blockIdx.x * blockDim.x + threadIdx.x; i < n;
       i += gridDim.x * blockDim.x)
    x[i] = x[i] * g + be;
}

extern "C" void kernel_launch(void* const* d_in, const int* in_sizes, int n_in,
                              void* d_out, int out_size, void* d_ws, size_t ws_size,
                              hipStream_t stream)
{
  const float* Qg    = (const float*)d_in[0];   // (32,256,17,17)
  const float* Sg    = (const float*)d_in[1];   // (32,256,65,65)
  const float* gamma = (const float*)d_in[2];   // (1,)
  const float* beta  = (const float*)d_in[3];   // (1,)
  float* out   = (float*)d_out;                 // (32,1,65,65) fp32
  float* stats = (float*)d_ws;                  // 2 floats

  hipMemsetAsync(d_out, 0, (size_t)out_size * sizeof(float), stream);
  hipMemsetAsync(d_ws, 0, 2 * sizeof(float), stream);

  corr_main<<<dim3(32 * 17 * 4), dim3(256), 0, stream>>>(Qg, Sg, out);
  corr_edge<<<dim3(520), dim3(256), 0, stream>>>(Qg, Sg, out);
  bn_reduce<<<dim3(256), dim3(256), 0, stream>>>(out, stats, out_size);
  bn_norm<<<dim3(512), dim3(256), 0, stream>>>(out, stats, gamma, beta, out_size);
}

// Round 4
// 492.075 us; speedup vs baseline: 3.6859x; 3.6859x over previous
//
#include <hip/hip_runtime.h>

// ---------------- problem constants ----------------
#define BS   32
#define CIN  256
#define QH   17
#define QW   17
#define HH   65
#define WW   65
#define PAD  8
#define M289 289            // i*17+j
#define MROWS 304           // 19 * 16 (M padded; rows 289..303 zero)
#define NPIX 4225           // 65*65 flat (v,x)
#define P2_N 4288           // 67*64 padded N
#define NBLK 67             // ceil(4225/64)
#define NTILE 64
#define KC   32             // channels per K-step

// ws layout: Qt bf16 [32][304][256], P2 bf16 [32][304][4288], stats
#define QT_BYTES  ((size_t)BS * MROWS * CIN * 2)          // 4,980,736
#define P2_BYTES  ((size_t)BS * MROWS * P2_N * 2)         // 83,427,328
#define WS_NEED   (QT_BYTES + P2_BYTES + 16)

typedef __attribute__((ext_vector_type(8))) short short8;
typedef __attribute__((ext_vector_type(4))) float f32x4;

__device__ __forceinline__ unsigned short f2bf(float f) {
  unsigned u = __float_as_uint(f);
  return (unsigned short)((u + 0x7FFFu + ((u >> 16) & 1u)) >> 16);   // RNE
}
__device__ __forceinline__ float bf2f(unsigned short h) {
  return __uint_as_float(((unsigned)h) << 16);
}

// ============ MFMA PATH ============

// P0: transpose Q[b][c][m] (m=i*17+j, 289) -> Qt[b][m][c] bf16, rows 289..303 = 0
__global__ __launch_bounds__(256) void qprep(
    const float* __restrict__ Q, unsigned short* __restrict__ Qt)
{
  __shared__ float T[64][65];
  const int bid = blockIdx.x;                 // 32 b * 4 ct * 5 mt = 640
  const int b  = bid / 20;
  const int rem = bid - b * 20;
  const int ct = rem / 5, mt = rem - (rem / 5) * 5;
  const int c0 = ct * 64, m0 = mt * 64;
  for (int idx = threadIdx.x; idx < 4096; idx += 256) {
    int cl = idx >> 6, ml = idx & 63;
    int m = m0 + ml;
    float v = (m < M289) ? Q[(size_t)(b * CIN + c0 + cl) * M289 + m] : 0.0f;
    T[cl][ml] = v;
  }
  __syncthreads();
  for (int idx = threadIdx.x; idx < 4096; idx += 256) {
    int ml = idx >> 6, cl = idx & 63;
    int m = m0 + ml;
    if (m < MROWS)
      Qt[(size_t)(b * MROWS + m) * CIN + c0 + cl] = f2bf(T[cl][ml]);
  }
}

// P1: per-b GEMM  P2[m][n] = sum_c Qt[m][c] * S[c][n]   (bf16 MFMA 16x16x32)
// block = (b, n-tile of 64). 4 waves: (mw: Mtiles 0-9 / 10-18) x (nw: 2 subtiles).
// LDS: AL slot (g,m) = Qt[m][c0+8g..+8); BL slot (g,n) = S[c0+8g..+8)][n0+n].
// Same k-order sigma(g,e)=8g+e for A and B (k-permutation self-cancels).
__global__ __launch_bounds__(256) void corr_gemm(
    const float* __restrict__ S, const unsigned short* __restrict__ Qt,
    unsigned short* __restrict__ P2)
{
  __shared__ uint4 AL[4 * 306 + 4];   // g-stride 306 (mod 8 = 2) -> conflict-floor writes
  __shared__ uint4 BL[4 * 72];        // n-skew: unit = g*72 + n + (n>>3)

  const int tid = threadIdx.x;
  const int bid = blockIdx.x;
  const int b  = bid / NBLK;
  const int nt = bid - b * NBLK;
  const int n0 = nt * NTILE;

  const int l  = tid & 63;
  const int w  = tid >> 6;
  const int mw = w >> 1;              // 0 or 1
  const int nw = w & 1;               // 0 or 1
  const int lr = l & 15;
  const int g  = l >> 4;

  const int nT    = mw ? 9 : 10;
  const int tbase = mw ? 10 : 0;

  f32x4 acc[10][2];
  #pragma unroll
  for (int t = 0; t < 10; ++t)
    #pragma unroll
    for (int s = 0; s < 2; ++s) acc[t][s] = (f32x4){0.f, 0.f, 0.f, 0.f};

  const unsigned short* QtB = Qt + (size_t)b * MROWS * CIN;
  const float* Sb = S + (size_t)b * CIN * NPIX;

  int bidx[2];
  #pragma unroll
  for (int s = 0; s < 2; ++s) {
    int n = (nw * 2 + s) * 16 + lr;
    bidx[s] = g * 72 + n + (n >> 3);
  }

  for (int kc = 0; kc < 8; ++kc) {
    const int c0 = kc * KC;
    // stage A: 304 m x 4 g, 16B each
    for (int idx = tid; idx < MROWS * 4; idx += 256) {
      int gg = idx & 3, m = idx >> 2;
      uint4 v = *(const uint4*)(QtB + (size_t)m * CIN + c0 + gg * 8);
      AL[gg * 306 + m] = v;
    }
    // stage B: 16 c-pairs x 64 n (clamped flat reads; garbage cols discarded)
    for (int idx = tid; idx < 16 * 64; idx += 256) {
      int p = idx >> 6;
      int n = idx & 63;
      int q = n0 + n; if (q > NPIX - 1) q = NPIX - 1;
      float v0 = Sb[(size_t)(c0 + 2 * p)     * NPIX + q];
      float v1 = Sb[(size_t)(c0 + 2 * p + 1) * NPIX + q];
      unsigned pk = (unsigned)f2bf(v0) | ((unsigned)f2bf(v1) << 16);
      ((unsigned*)BL)[((p >> 2) * 72 + n + (n >> 3)) * 4 + (p & 3)] = pk;
    }
    __syncthreads();

    short8 bf[2];
    #pragma unroll
    for (int s = 0; s < 2; ++s) bf[s] = *(const short8*)&BL[bidx[s]];
    #pragma unroll
    for (int t = 0; t < 10; ++t) {
      if (t < nT) {
        short8 af = *(const short8*)&AL[g * 306 + (tbase + t) * 16 + lr];
        #pragma unroll
        for (int s = 0; s < 2; ++s)
          acc[t][s] = __builtin_amdgcn_mfma_f32_16x16x32_bf16(
              af, bf[s], acc[t][s], 0, 0, 0);
      }
    }
    __syncthreads();
  }

  // epilogue: C/D layout (verified m89): col = lane&15, row = (lane>>4)*4 + reg
  #pragma unroll
  for (int t = 0; t < 10; ++t) {
    if (t < nT) {
      #pragma unroll
      for (int s = 0; s < 2; ++s) {
        int nl = (nw * 2 + s) * 16 + lr;
        #pragma unroll
        for (int r = 0; r < 4; ++r) {
          int m = (tbase + t) * 16 + g * 4 + r;
          P2[(size_t)(b * MROWS + m) * P2_N + n0 + nl] = f2bf(acc[t][s][r]);
        }
      }
    }
  }
}

// P2-gather + corr write + BN stats partials
__global__ __launch_bounds__(256) void gather_bn(
    const unsigned short* __restrict__ P2, float* __restrict__ out,
    float* __restrict__ stats)
{
  const int tid  = threadIdx.x;
  const int b    = blockIdx.x / 17;
  const int yt   = blockIdx.x - b * 17;
  const int y    = yt * 4 + (tid >> 6);
  const int lane = tid & 63;
  float sa = 0.f, sq = 0.f;

  if (y < HH) {
    const unsigned short* Pb = P2 + (size_t)b * MROWS * P2_N;
    for (int x = lane; x < WW; x += 64) {
      float acc = 0.f;
      for (int i = 0; i < QH; ++i) {            // v-condition wave-uniform
        int v = y + i - PAD;
        if ((unsigned)v < (unsigned)HH) {
          long long base = (long long)(i * QW) * P2_N + (long long)v * WW + x - PAD;
          #pragma unroll
          for (int j = 0; j < QW; ++j) {
            int u = x + j - PAD;
            if ((unsigned)u < (unsigned)WW)
              acc += bf2f(Pb[base + (long long)j * (P2_N + 1)]);
          }
        }
      }
      out[((size_t)b * HH + y) * WW + x] = acc;
      sa += acc; sq += acc * acc;
    }
  }
  #pragma unroll
  for (int off = 32; off; off >>= 1) {
    sa += __shfl_down(sa, off, 64);
    sq += __shfl_down(sq, off, 64);
  }
  __shared__ float pa[4], pq[4];
  if (lane == 0) { pa[tid >> 6] = sa; pq[tid >> 6] = sq; }
  __syncthreads();
  if (tid == 0) {
    atomicAdd(&stats[0], pa[0] + pa[1] + pa[2] + pa[3]);
    atomicAdd(&stats[1], pq[0] + pq[1] + pq[2] + pq[3]);
  }
}

// in-place training-mode BN normalize
__global__ __launch_bounds__(256) void bn_norm(
    float* __restrict__ x, const float* __restrict__ stats,
    const float* __restrict__ gamma, const float* __restrict__ beta, int n)
{
  const float invn = 1.0f / (float)n;
  const float mean = stats[0] * invn;
  const float var  = stats[1] * invn - mean * mean;
  const float inv  = rsqrtf(var + 1e-5f);
  const float gm = gamma[0] * inv;
  const float be = beta[0] - mean * gm;
  for (int i = blockIdx.x * blockDim.x + threadIdx.x; i < n;
       i += gridDim.x * blockDim.x)
    x[i] = x[i] * gm + be;
}

// ============ FALLBACK PATH (round-3, verified correct) ============
#define YT  4
#define CCHUNK 16
#define NVMAX 20

__global__ __launch_bounds__(256) void corr_main(
    const float* __restrict__ Qg, const float* __restrict__ Sg,
    float* __restrict__ out)
{
  const int lane = threadIdx.x & 63;
  const int w    = threadIdx.x >> 6;
  const int bid = blockIdx.x;
  const int cb  = bid & 3;
  const int t   = bid >> 2;
  const int yt  = t % 17;
  const int b   = t / 17;
  const int y0  = yt * YT;
  const int c0  = (cb * 4 + w) * CCHUNK;

  __shared__ float sbuf[4][NVMAX][96];
  __shared__ float red[4][YT][64];

  int vlo = y0 - PAD;            if (vlo < 0) vlo = 0;
  int vhi = y0 + (YT - 1) + PAD; if (vhi > HH - 1) vhi = HH - 1;
  const int nv = vhi - vlo + 1;

  for (int idx = threadIdx.x; idx < 4 * NVMAX * 96; idx += 256)
    ((float*)sbuf)[idx] = 0.0f;
  __syncthreads();

  float acc[YT] = {0.0f, 0.0f, 0.0f, 0.0f};
  for (int cc = 0; cc < CCHUNK; ++cc) {
    const int c = c0 + cc;
    const float* __restrict__ Sc = Sg + ((size_t)(b * CIN + c) * HH) * WW;
    const float* __restrict__ Qc = Qg + ((size_t)(b * CIN + c) * QH) * QW;
    for (int vv = 0; vv < nv; ++vv) {
      const float* __restrict__ srow = Sc + (vlo + vv) * WW;
      sbuf[w][vv][PAD + lane] = srow[lane];
      if (lane == 0) sbuf[w][vv][PAD + 64] = srow[64];
    }
    __syncthreads();
    for (int vv = 0; vv < nv; ++vv) {
      float s[QW];
      #pragma unroll
      for (int j = 0; j < QW; ++j) s[j] = sbuf[w][vv][lane + j];
      const int ibase = (vlo + vv) - y0 + PAD;
      #pragma unroll
      for (int dy = 0; dy < YT; ++dy) {
        const int i = ibase - dy;
        if ((unsigned)i < (unsigned)QH) {
          const float* __restrict__ qrow = Qc + i * QW;
          #pragma unroll
          for (int j = 0; j < QW; ++j)
            acc[dy] = fmaf(s[j], qrow[j], acc[dy]);
        }
      }
    }
    __syncthreads();
  }
  #pragma unroll
  for (int dy = 0; dy < YT; ++dy) red[w][dy][lane] = acc[dy];
  __syncthreads();
  if (w == 0) {
    #pragma unroll
    for (int dy = 0; dy < YT; ++dy) {
      const int y = y0 + dy;
      if (y < HH) {
        float tsum = red[0][dy][lane] + red[1][dy][lane]
                   + red[2][dy][lane] + red[3][dy][lane];
        atomicAdd(&out[((size_t)b * HH + y) * WW + lane], tsum);
      }
    }
  }
}

__global__ __launch_bounds__(256) void corr_edge(
    const float* __restrict__ Qg, const float* __restrict__ Sg,
    float* __restrict__ out)
{
  const int lane = threadIdx.x & 63;
  const int w = threadIdx.x >> 6;
  const int wid = blockIdx.x * 4 + w;
  const int b = wid / HH;
  const int y = wid - b * HH;
  float acc = 0.0f;
  for (int c = 0; c < CIN; ++c) {
    const float* __restrict__ Sc = Sg + ((size_t)(b * CIN + c) * HH) * WW;
    const float* __restrict__ Qc = Qg + ((size_t)(b * CIN + c) * QH) * QW;
    #pragma unroll
    for (int r = 0; r < 3; ++r) {
      const int tp = lane + r * 64;
      if (tp < QH * 9) {
        const int i = tp / 9;
        const int j = tp - i * 9;
        const int v = y + i - PAD;
        if ((unsigned)v < (unsigned)HH)
          acc += Sc[v * WW + (WW - 9) + j] * Qc[i * QW + j];
      }
    }
  }
  #pragma unroll
  for (int off = 32; off; off >>= 1) acc += __shfl_down(acc, off, 64);
  if (lane == 0) out[((size_t)b * HH + y) * WW + (WW - 1)] = acc;
}

__global__ __launch_bounds__(256) void bn_reduce(
    const float* __restrict__ x, float* __restrict__ stats, int n)
{
  float a = 0.0f, q = 0.0f;
  for (int i = blockIdx.x * blockDim.x + threadIdx.x; i < n;
       i += gridDim.x * blockDim.x) {
    float v = x[i];
    a += v; q += v * v;
  }
  #pragma unroll
  for (int off = 32; off; off >>= 1) {
    a += __shfl_down(a, off, 64);
    q += __shfl_down(q, off, 64);
  }
  __shared__ float sa[4], sq[4];
  const int w = threadIdx.x >> 6, lane = threadIdx.x & 63;
  if (lane == 0) { sa[w] = a; sq[w] = q; }
  __syncthreads();
  if (threadIdx.x == 0) {
    atomicAdd(&stats[0], sa[0] + sa[1] + sa[2] + sa[3]);
    atomicAdd(&stats[1], sq[0] + sq[1] + sq[2] + sq[3]);
  }
}

// ============ launcher ============
extern "C" void kernel_launch(void* const* d_in, const int* in_sizes, int n_in,
                              void* d_out, int out_size, void* d_ws, size_t ws_size,
                              hipStream_t stream)
{
  const float* Qg    = (const float*)d_in[0];   // (32,256,17,17)
  const float* Sg    = (const float*)d_in[1];   // (32,256,65,65)
  const float* gamma = (const float*)d_in[2];
  const float* beta  = (const float*)d_in[3];
  float* out = (float*)d_out;

  if (ws_size >= WS_NEED) {
    unsigned short* Qt = (unsigned short*)d_ws;
    unsigned short* P2 = (unsigned short*)((char*)d_ws + QT_BYTES);
    float* stats       = (float*)((char*)d_ws + QT_BYTES + P2_BYTES);
    hipMemsetAsync(stats, 0, 16, stream);
    qprep<<<dim3(640), dim3(256), 0, stream>>>(Qg, Qt);
    corr_gemm<<<dim3(BS * NBLK), dim3(256), 0, stream>>>(Sg, Qt, P2);
    gather_bn<<<dim3(BS * 17), dim3(256), 0, stream>>>(P2, out, stats);
    bn_norm<<<dim3(512), dim3(256), 0, stream>>>(out, stats, gamma, beta, out_size);
  } else {
    float* stats = (float*)d_ws;
    hipMemsetAsync(d_out, 0, (size_t)out_size * sizeof(float), stream);
    hipMemsetAsync(d_ws, 0, 2 * sizeof(float), stream);
    corr_main<<<dim3(BS * 17 * 4), dim3(256), 0, stream>>>(Qg, Sg, out);
    corr_edge<<<dim3(520), dim3(256), 0, stream>>>(Qg, Sg, out);
    bn_reduce<<<dim3(256), dim3(256), 0, stream>>>(out, stats, out_size);
    bn_norm<<<dim3(512), dim3(256), 0, stream>>>(out, stats, gamma, beta, out_size);
  }
}